// Round 1
// baseline (541.380 us; speedup 1.0000x reference)
//
#include <hip/hip_runtime.h>

// ---------------------------------------------------------------------------
// SympleAgent Tree-LSTM on MI355X, fp32 baseline.
// Restructure: leaf table + level-10 table trick + per-level fused GEMM.
// ---------------------------------------------------------------------------

__device__ __forceinline__ float fsig(float x) {
    return __fdividef(1.0f, 1.0f + __expf(-x));
}
__device__ __forceinline__ float ftanh(float x) {
    // tanh(x) = 1 - 2/(exp(2x)+1); saturates correctly for large |x|
    return 1.0f - __fdividef(2.0f, __expf(2.0f * x) + 1.0f);
}

// ---------------- precompute: leaf tables, Wxb, Ta/Tb, combined U ----------
// grid 128 (one block per vocab id), block 320 threads (5 waves)
__global__ void precompute_kernel(
    const float* __restrict__ Wx, const float* __restrict__ b_tree,
    const float* __restrict__ Ua, const float* __restrict__ Ub,
    float* __restrict__ Wxb, float* __restrict__ Ucomb,
    float* __restrict__ leaf_h, float* __restrict__ leaf_c,
    float* __restrict__ Ta, float* __restrict__ Tb)
{
    int v = blockIdx.x;
    int t = threadIdx.x;
    __shared__ float sz[320];
    __shared__ float sh[64];
    float z = Wx[v * 320 + t] + b_tree[t];
    Wxb[v * 320 + t] = z;
    sz[t] = z;
    // combined U: rows 0..63 = Ua, rows 64..127 = Ub (v spans exactly 0..127)
    Ucomb[v * 320 + t] = (v < 64) ? Ua[v * 320 + t] : Ub[(v - 64) * 320 + t];
    __syncthreads();
    if (t < 64) {
        // leaf: c = sig(i)*tanh(u); h = sig(o)*tanh(c)
        float c = fsig(sz[t]) * ftanh(sz[256 + t]);
        float h = fsig(sz[192 + t]) * ftanh(c);
        leaf_c[v * 64 + t] = c;
        leaf_h[v * 64 + t] = h;
        sh[t] = h;
    }
    __syncthreads();
    float ta = 0.f, tb = 0.f;
    #pragma unroll
    for (int k = 0; k < 64; ++k) {
        ta += sh[k] * Ua[k * 320 + t];
        tb += sh[k] * Ub[k * 320 + t];
    }
    Ta[v * 320 + t] = ta;
    Tb[v * 320 + t] = tb;
}

// ---------------- level 10: pure table gather + pointwise ------------------
// 131072 rows, 4 rows/block (one wave per row), grid 32768 x 256
__global__ void level10_kernel(
    const int* __restrict__ x_idx,
    const float* __restrict__ Wxb, const float* __restrict__ Ta,
    const float* __restrict__ Tb, const float* __restrict__ leaf_c,
    float* __restrict__ h_out, float* __restrict__ c_out)
{
    int row  = blockIdx.x * 4 + (threadIdx.x >> 6);
    int lane = threadIdx.x & 63;
    int b = row >> 10;          // batch
    int i = row & 1023;         // node within level 10
    const int* xb = x_idx + b * 4095;
    int id  = xb[1023 + i];         // this node
    int ida = xb[2047 + 2 * i];     // left child (leaf)
    int idb = xb[2048 + 2 * i];     // right child (leaf)
    const float* w  = Wxb + id  * 320 + lane;
    const float* ta = Ta  + ida * 320 + lane;
    const float* tb = Tb  + idb * 320 + lane;
    float zi  = w[0]   + ta[0]   + tb[0];
    float zfa = w[64]  + ta[64]  + tb[64];
    float zfb = w[128] + ta[128] + tb[128];
    float zo  = w[192] + ta[192] + tb[192];
    float zu  = w[256] + ta[256] + tb[256];
    float ca = leaf_c[ida * 64 + lane];
    float cb = leaf_c[idb * 64 + lane];
    float c = fsig(zi) * ftanh(zu) + fsig(zfa) * ca + fsig(zfb) * cb;
    float h = fsig(zo) * ftanh(c);
    h_out[row * 64 + lane] = h;
    c_out[row * 64 + lane] = c;
}

// ---------------- levels 9..0: fused GEMM (M,128)x(128,320) + epilogue -----
// block 256 = 4 waves; TM=64 rows/block; wave handles 16 rows x 320 cols;
// thread tile = 16 rows x 5 cols (cols lane, lane+64, ..., lane+256 =
// gates i,fa,fb,o,u at hidden index `lane` -> epilogue is in-register).
#define TM 64
#define KC 32
__global__ __launch_bounds__(256) void level_kernel(
    const float* __restrict__ h_prev, const float* __restrict__ c_prev,
    const float* __restrict__ Ucomb, const float* __restrict__ Wxb,
    const int* __restrict__ x_idx, int dshift,
    float* __restrict__ h_out, float* __restrict__ c_out)
{
    __shared__ float sU[KC * 320];        // 40 KB, contiguous chunk of Ucomb
    __shared__ float sA[TM][KC + 4];      // +4 pad: conflict-free f4 writes
    int t    = threadIdx.x;
    int lane = t & 63;
    int wv   = t >> 6;                    // wave id 0..3
    int row0 = blockIdx.x * TM;

    float acc[16][5];
    #pragma unroll
    for (int r = 0; r < 16; ++r)
        #pragma unroll
        for (int j = 0; j < 5; ++j) acc[r][j] = 0.f;

    const float* Abase = h_prev + (size_t)row0 * 128;

    for (int kc = 0; kc < 4; ++kc) {
        // stage U chunk (rows kc*32..kc*32+31 of Ucomb, contiguous 40 KB)
        {
            const float4* src = (const float4*)(Ucomb + kc * (KC * 320));
            float4* dst = (float4*)sU;
            #pragma unroll
            for (int it = 0; it < (KC * 320 / 4) / 256; ++it)
                dst[t + it * 256] = src[t + it * 256];
        }
        // stage A tile: 64 rows x 32 k
        {
            #pragma unroll
            for (int it = 0; it < (TM * KC / 4) / 256; ++it) {
                int idx = t + it * 256;
                int r = idx >> 3, kk4 = idx & 7;
                *(float4*)&sA[r][kk4 * 4] =
                    *(const float4*)&Abase[(size_t)r * 128 + kc * KC + kk4 * 4];
            }
        }
        __syncthreads();
        #pragma unroll 2
        for (int k4 = 0; k4 < KC; k4 += 4) {
            float u[4][5];
            #pragma unroll
            for (int kk = 0; kk < 4; ++kk)
                #pragma unroll
                for (int j = 0; j < 5; ++j)
                    u[kk][j] = sU[(k4 + kk) * 320 + lane + 64 * j];
            #pragma unroll
            for (int r = 0; r < 16; ++r) {
                float4 a4 = *(const float4*)&sA[wv * 16 + r][k4];  // broadcast
                float av;
                av = a4.x;
                acc[r][0] += av * u[0][0]; acc[r][1] += av * u[0][1];
                acc[r][2] += av * u[0][2]; acc[r][3] += av * u[0][3];
                acc[r][4] += av * u[0][4];
                av = a4.y;
                acc[r][0] += av * u[1][0]; acc[r][1] += av * u[1][1];
                acc[r][2] += av * u[1][2]; acc[r][3] += av * u[1][3];
                acc[r][4] += av * u[1][4];
                av = a4.z;
                acc[r][0] += av * u[2][0]; acc[r][1] += av * u[2][1];
                acc[r][2] += av * u[2][2]; acc[r][3] += av * u[2][3];
                acc[r][4] += av * u[2][4];
                av = a4.w;
                acc[r][0] += av * u[3][0]; acc[r][1] += av * u[3][1];
                acc[r][2] += av * u[3][2]; acc[r][3] += av * u[3][3];
                acc[r][4] += av * u[3][4];
            }
        }
        __syncthreads();
    }

    // fused epilogue: gather Wxb[id], gates, c-recurrence, store h/c
    int n = 1 << dshift;
    int off = n - 1;
    #pragma unroll
    for (int r = 0; r < 16; ++r) {
        int row = row0 + wv * 16 + r;
        int b = row >> dshift;
        int i = row & (n - 1);
        int id = x_idx[b * 4095 + off + i];
        const float* w = Wxb + id * 320 + lane;
        float zi  = acc[r][0] + w[0];
        float zfa = acc[r][1] + w[64];
        float zfb = acc[r][2] + w[128];
        float zo  = acc[r][3] + w[192];
        float zu  = acc[r][4] + w[256];
        float ca = c_prev[(size_t)row * 128 + lane];
        float cb = c_prev[(size_t)row * 128 + 64 + lane];
        float c = fsig(zi) * ftanh(zu) + fsig(zfa) * ca + fsig(zfb) * cb;
        float h = fsig(zo) * ftanh(c);
        h_out[(size_t)row * 64 + lane] = h;
        c_out[(size_t)row * 64 + lane] = c;
    }
}

// ---------------- head: MLP + LSTM cell + actor softmax --------------------
// grid 128 (one block per batch row), block 64
__global__ void head_kernel(
    const float* __restrict__ h_root,
    const float* __restrict__ W1, const float* __restrict__ b1,
    const float* __restrict__ W2, const float* __restrict__ b2,
    const float* __restrict__ W_ih, const float* __restrict__ b_lstm,
    const float* __restrict__ actor_W, const float* __restrict__ actor_b,
    const float* __restrict__ vm, float* __restrict__ out)
{
    int b = blockIdx.x, t = threadIdx.x;
    __shared__ float shh[64], sr1[64], sf[64], sfeat[128], slg[20];
    shh[t] = h_root[b * 64 + t];
    __syncthreads();
    float a = b1[t];
    #pragma unroll
    for (int k = 0; k < 64; ++k) a += shh[k] * W1[k * 64 + t];
    sr1[t] = fmaxf(a, 0.f);
    __syncthreads();
    float f = b2[t];
    #pragma unroll
    for (int k = 0; k < 64; ++k) f += sr1[k] * W2[k * 64 + t];
    sf[t] = f;
    sfeat[t] = f;
    __syncthreads();
    // LSTM cell with h0 = 0: only i, gg, o gates matter (fg multiplies c0=0)
    float gi = b_lstm[t], gg = b_lstm[128 + t], go = b_lstm[192 + t];
    #pragma unroll
    for (int k = 0; k < 64; ++k) {
        float fk = sf[k];
        gi += fk * W_ih[k * 256 + t];
        gg += fk * W_ih[k * 256 + 128 + t];
        go += fk * W_ih[k * 256 + 192 + t];
    }
    float cg = fsig(gi) * ftanh(gg);
    float hg = fsig(go) * ftanh(cg);
    sfeat[64 + t] = hg;
    __syncthreads();
    if (t < 20) {
        float m = vm[t];
        float dot = 0.f;
        #pragma unroll
        for (int k = 0; k < 128; ++k) dot += sfeat[k] * actor_W[k * 20 + t];
        slg[t] = logf(m) + dot * m + actor_b[t] * m;
    }
    __syncthreads();
    if (t < 20) {
        float mx = -1e30f;
        #pragma unroll
        for (int j = 0; j < 20; ++j) mx = fmaxf(mx, slg[j]);
        float s = 0.f;
        #pragma unroll
        for (int j = 0; j < 20; ++j) s += __expf((slg[j] - mx) * (1.0f / 3.0f));
        float e = __expf((slg[t] - mx) * (1.0f / 3.0f));
        out[b * 20 + t] = e / s;
    }
}

// ---------------------------------------------------------------------------
extern "C" void kernel_launch(void* const* d_in, const int* in_sizes, int n_in,
                              void* d_out, int out_size, void* d_ws, size_t ws_size,
                              hipStream_t stream)
{
    const int*   x_idx   = (const int*)d_in[0];
    const float* vm      = (const float*)d_in[1];
    const float* Wx      = (const float*)d_in[2];
    const float* Ua      = (const float*)d_in[3];
    const float* Ub      = (const float*)d_in[4];
    const float* b_tree  = (const float*)d_in[5];
    const float* W_ih    = (const float*)d_in[6];
    // d_in[7] = W_hh, unused (h0 = 0)
    const float* b_lstm  = (const float*)d_in[8];
    const float* W1      = (const float*)d_in[9];
    const float* b1      = (const float*)d_in[10];
    const float* W2      = (const float*)d_in[11];
    const float* b2      = (const float*)d_in[12];
    const float* actor_W = (const float*)d_in[13];
    const float* actor_b = (const float*)d_in[14];
    float* out = (float*)d_out;

    float* ws = (float*)d_ws;
    float* Wxb    = ws;  ws += 128 * 320;
    float* Ucomb  = ws;  ws += 128 * 320;
    float* leaf_h = ws;  ws += 128 * 64;
    float* leaf_c = ws;  ws += 128 * 64;
    float* Ta     = ws;  ws += 128 * 320;
    float* Tb     = ws;  ws += 128 * 320;
    // ping-pong h/c. buf0 first written at level 10 (131072 rows x 64),
    // buf1 first written at level 9 (65536 rows x 64) -> can be half-size.
    float* hb0 = ws;  ws += 128 * 1024 * 64;
    float* cb0 = ws;  ws += 128 * 1024 * 64;
    float* hb1 = ws;  ws += 128 * 512 * 64;
    float* cb1 = ws;  ws += 128 * 512 * 64;
    float* hb[2] = { hb0, hb1 };
    float* cb[2] = { cb0, cb1 };

    precompute_kernel<<<128, 320, 0, stream>>>(Wx, b_tree, Ua, Ub,
                                               Wxb, Ucomb, leaf_h, leaf_c, Ta, Tb);
    level10_kernel<<<131072 / 4, 256, 0, stream>>>(x_idx, Wxb, Ta, Tb, leaf_c,
                                                   hb[0], cb[0]);
    int cur = 0;
    for (int d = 9; d >= 0; --d) {
        int M = 128 << d;
        level_kernel<<<M / TM, 256, 0, stream>>>(hb[cur], cb[cur], Ucomb, Wxb,
                                                 x_idx, d, hb[cur ^ 1], cb[cur ^ 1]);
        cur ^= 1;
    }
    head_kernel<<<128, 64, 0, stream>>>(hb[cur], W1, b1, W2, b2, W_ih, b_lstm,
                                        actor_W, actor_b, vm, out);
}

// Round 2
// 334.527 us; speedup vs baseline: 1.6183x; 1.6183x over previous
//
#include <hip/hip_runtime.h>

// ---------------------------------------------------------------------------
// SympleAgent Tree-LSTM on MI355X.
// R2: bf16 MFMA (16x16x32) for the per-level GEMMs, fp32 everywhere else.
// Leaf table + level-10 table trick retained from R1.
// ---------------------------------------------------------------------------

typedef unsigned short u16;
typedef __attribute__((ext_vector_type(8))) short short8;   // 8 bf16 = 4 VGPRs
typedef __attribute__((ext_vector_type(4))) float floatx4;  // MFMA C/D frag

__device__ __forceinline__ float fsig(float x) {
    return __fdividef(1.0f, 1.0f + __expf(-x));
}
__device__ __forceinline__ float ftanh(float x) {
    return 1.0f - __fdividef(2.0f, __expf(2.0f * x) + 1.0f);
}
__device__ __forceinline__ u16 f2bf(float x) {   // round-to-nearest-even
    unsigned u = __float_as_uint(x);
    return (u16)((u + 0x7FFFu + ((u >> 16) & 1u)) >> 16);
}
// async global->LDS, 16B per lane; LDS dest = base + lane*16 (wave-uniform base)
__device__ __forceinline__ void async_ld16(const u16* g, u16* l) {
    __builtin_amdgcn_global_load_lds(
        (const __attribute__((address_space(1))) unsigned int*)g,
        (__attribute__((address_space(3))) unsigned int*)l, 16, 0, 0);
}

// ---------------- precompute: Wxb, leaf tables, Ta/Tb, swizzled bf16 U -----
// grid 128 (one block per vocab id), block 320 threads
// Uswz fragment layout: f = ((kc*20 + nt)*64 + lane)*8 + j  holds
//   U[kc*32 + (lane>>4)*8 + j][nt*16 + (lane&15)]   (U = vstack(Ua,Ub), 128x320)
__global__ void precompute_kernel(
    const float* __restrict__ Wx, const float* __restrict__ b_tree,
    const float* __restrict__ Ua, const float* __restrict__ Ub,
    float* __restrict__ Wxb, u16* __restrict__ Uswz,
    float* __restrict__ leaf_c, float* __restrict__ Ta, float* __restrict__ Tb)
{
    int v = blockIdx.x;
    int t = threadIdx.x;
    __shared__ float sz[320];
    __shared__ float sh[64];
    float z = Wx[v * 320 + t] + b_tree[t];
    Wxb[v * 320 + t] = z;
    sz[t] = z;
    // bf16 swizzled U (40960 elements == 128*320 threads, one each)
    {
        int f = v * 320 + t;
        int j = f & 7, lane = (f >> 3) & 63, tk = f >> 9;
        int nt = tk % 20, kc = tk / 20;
        int k = kc * 32 + (lane >> 4) * 8 + j;
        int nn = nt * 16 + (lane & 15);
        float uval = (k < 64) ? Ua[k * 320 + nn] : Ub[(k - 64) * 320 + nn];
        Uswz[f] = f2bf(uval);
    }
    __syncthreads();
    if (t < 64) {
        float c = fsig(sz[t]) * ftanh(sz[256 + t]);
        float h = fsig(sz[192 + t]) * ftanh(c);
        leaf_c[v * 64 + t] = c;
        sh[t] = h;
    }
    __syncthreads();
    float ta = 0.f, tb = 0.f;
    #pragma unroll
    for (int k = 0; k < 64; ++k) {
        ta += sh[k] * Ua[k * 320 + t];
        tb += sh[k] * Ub[k * 320 + t];
    }
    Ta[v * 320 + t] = ta;
    Tb[v * 320 + t] = tb;
}

// ---------------- level 10: pure table gather + pointwise ------------------
__global__ void level10_kernel(
    const int* __restrict__ x_idx,
    const float* __restrict__ Wxb, const float* __restrict__ Ta,
    const float* __restrict__ Tb, const float* __restrict__ leaf_c,
    u16* __restrict__ h_out, float* __restrict__ c_out)
{
    int row  = blockIdx.x * 4 + (threadIdx.x >> 6);
    int lane = threadIdx.x & 63;
    int b = row >> 10;
    int i = row & 1023;
    const int* xb = x_idx + b * 4095;
    int id  = xb[1023 + i];
    int ida = xb[2047 + 2 * i];
    int idb = xb[2048 + 2 * i];
    const float* w  = Wxb + id  * 320 + lane;
    const float* ta = Ta  + ida * 320 + lane;
    const float* tb = Tb  + idb * 320 + lane;
    float zi  = w[0]   + ta[0]   + tb[0];
    float zfa = w[64]  + ta[64]  + tb[64];
    float zfb = w[128] + ta[128] + tb[128];
    float zo  = w[192] + ta[192] + tb[192];
    float zu  = w[256] + ta[256] + tb[256];
    float ca = leaf_c[ida * 64 + lane];
    float cb = leaf_c[idb * 64 + lane];
    float c = fsig(zi) * ftanh(zu) + fsig(zfa) * ca + fsig(zfb) * cb;
    float h = fsig(zo) * ftanh(c);
    h_out[row * 64 + lane] = f2bf(h);
    c_out[row * 64 + lane] = c;
}

// ---------------- levels 9..0: MFMA GEMM (M,128)x(128,320) + epilogue ------
// block 256 = 4 waves, 128 rows/block (wave: 32 rows = 2 m-tiles of 16).
// K=128 in 4 chunks of 32 (one 16x16x32 mfma per chunk per tile).
// B (Uswz) double-buffered in LDS via global_load_lds; A straight from global.
__global__ __launch_bounds__(256, 2) void level_kernel(
    const u16* __restrict__ h_prev, const float* __restrict__ c_prev,
    const u16* __restrict__ Uswz, const float* __restrict__ Wxb,
    const int* __restrict__ x_idx, int dshift,
    u16* __restrict__ h_out, float* __restrict__ c_out,
    float* __restrict__ hroot)
{
    __shared__ u16 sB[2][20 * 64 * 8];   // 2 x 20 KB
    int t = threadIdx.x;
    int lane = t & 63, wv = t >> 6;
    int lane15 = lane & 15, quad = lane >> 4;
    int row0 = blockIdx.x * 128 + wv * 32;

    floatx4 acc[2][20];
    #pragma unroll
    for (int mt = 0; mt < 2; ++mt)
        #pragma unroll
        for (int nt = 0; nt < 20; ++nt)
            acc[mt][nt] = (floatx4){0.f, 0.f, 0.f, 0.f};

    // prologue: stage chunk 0 (this wave's 5 KB slice)
    #pragma unroll
    for (int i = 0; i < 5; ++i) {
        int widx = wv * 5 + i;
        async_ld16(Uswz + widx * 512 + lane * 8, &sB[0][widx * 512]);
    }

    for (int kc = 0; kc < 4; ++kc) {
        // A fragments straight from global (16B/lane, rows read exactly once)
        short8 a0 = *(const short8*)(h_prev + (size_t)(row0 + lane15) * 128 + kc * 32 + quad * 8);
        short8 a1 = *(const short8*)(h_prev + (size_t)(row0 + 16 + lane15) * 128 + kc * 32 + quad * 8);
        __syncthreads();   // drains this wave's stage loads for buf kc&1
        if (kc < 3) {      // prefetch next chunk into the other buffer
            #pragma unroll
            for (int i = 0; i < 5; ++i) {
                int widx = wv * 5 + i;
                async_ld16(Uswz + (kc + 1) * 10240 + widx * 512 + lane * 8,
                           &sB[(kc + 1) & 1][widx * 512]);
            }
        }
        const u16* bb = sB[kc & 1];
        #pragma unroll
        for (int nt = 0; nt < 20; ++nt) {
            short8 b = *(const short8*)(bb + (nt * 64 + lane) * 8);
            acc[0][nt] = __builtin_amdgcn_mfma_f32_16x16x32_bf16(a0, b, acc[0][nt], 0, 0, 0);
            acc[1][nt] = __builtin_amdgcn_mfma_f32_16x16x32_bf16(a1, b, acc[1][nt], 0, 0, 0);
        }
    }

    // epilogue: C/D frag (row = quad*4+reg, col = lane&15 within 16x16 tile)
    // lane owns all 5 gates of (row, hh): gate g of hh sits in tile hb + 4g.
    int n = 1 << dshift, off = n - 1;
    #pragma unroll
    for (int mt = 0; mt < 2; ++mt) {
        #pragma unroll
        for (int r = 0; r < 4; ++r) {
            int row = row0 + mt * 16 + quad * 4 + r;
            int b = row >> dshift;
            int i = row & (n - 1);
            int id = x_idx[b * 4095 + off + i];
            const float* w = Wxb + id * 320;
            #pragma unroll
            for (int hb = 0; hb < 4; ++hb) {
                int hh = hb * 16 + lane15;
                float zi  = acc[mt][hb +  0][r] + w[hh];
                float zfa = acc[mt][hb +  4][r] + w[hh + 64];
                float zfb = acc[mt][hb +  8][r] + w[hh + 128];
                float zo  = acc[mt][hb + 12][r] + w[hh + 192];
                float zu  = acc[mt][hb + 16][r] + w[hh + 256];
                float ca = c_prev[(size_t)row * 128 + hh];
                float cb = c_prev[(size_t)row * 128 + 64 + hh];
                float c = fsig(zi) * ftanh(zu) + fsig(zfa) * ca + fsig(zfb) * cb;
                float h = fsig(zo) * ftanh(c);
                c_out[(size_t)row * 64 + hh] = c;
                h_out[(size_t)row * 64 + hh] = f2bf(h);
                if (hroot) hroot[row * 64 + hh] = h;   // fp32 root for the head
            }
        }
    }
}

// ---------------- head: MLP + LSTM cell + actor softmax --------------------
__global__ void head_kernel(
    const float* __restrict__ h_root,
    const float* __restrict__ W1, const float* __restrict__ b1,
    const float* __restrict__ W2, const float* __restrict__ b2,
    const float* __restrict__ W_ih, const float* __restrict__ b_lstm,
    const float* __restrict__ actor_W, const float* __restrict__ actor_b,
    const float* __restrict__ vm, float* __restrict__ out)
{
    int b = blockIdx.x, t = threadIdx.x;
    __shared__ float shh[64], sr1[64], sf[64], sfeat[128], slg[20];
    shh[t] = h_root[b * 64 + t];
    __syncthreads();
    float a = b1[t];
    #pragma unroll
    for (int k = 0; k < 64; ++k) a += shh[k] * W1[k * 64 + t];
    sr1[t] = fmaxf(a, 0.f);
    __syncthreads();
    float f = b2[t];
    #pragma unroll
    for (int k = 0; k < 64; ++k) f += sr1[k] * W2[k * 64 + t];
    sf[t] = f;
    sfeat[t] = f;
    __syncthreads();
    float gi = b_lstm[t], gg = b_lstm[128 + t], go = b_lstm[192 + t];
    #pragma unroll
    for (int k = 0; k < 64; ++k) {
        float fk = sf[k];
        gi += fk * W_ih[k * 256 + t];
        gg += fk * W_ih[k * 256 + 128 + t];
        go += fk * W_ih[k * 256 + 192 + t];
    }
    float cg = fsig(gi) * ftanh(gg);
    float hg = fsig(go) * ftanh(cg);
    sfeat[64 + t] = hg;
    __syncthreads();
    if (t < 20) {
        float m = vm[t];
        float dot = 0.f;
        #pragma unroll
        for (int k = 0; k < 128; ++k) dot += sfeat[k] * actor_W[k * 20 + t];
        slg[t] = logf(m) + dot * m + actor_b[t] * m;
    }
    __syncthreads();
    if (t < 20) {
        float mx = -1e30f;
        #pragma unroll
        for (int j = 0; j < 20; ++j) mx = fmaxf(mx, slg[j]);
        float s = 0.f;
        #pragma unroll
        for (int j = 0; j < 20; ++j) s += __expf((slg[j] - mx) * (1.0f / 3.0f));
        float e = __expf((slg[t] - mx) * (1.0f / 3.0f));
        out[b * 20 + t] = e / s;
    }
}

// ---------------------------------------------------------------------------
extern "C" void kernel_launch(void* const* d_in, const int* in_sizes, int n_in,
                              void* d_out, int out_size, void* d_ws, size_t ws_size,
                              hipStream_t stream)
{
    const int*   x_idx   = (const int*)d_in[0];
    const float* vm      = (const float*)d_in[1];
    const float* Wx      = (const float*)d_in[2];
    const float* Ua      = (const float*)d_in[3];
    const float* Ub      = (const float*)d_in[4];
    const float* b_tree  = (const float*)d_in[5];
    const float* W_ih    = (const float*)d_in[6];
    const float* b_lstm  = (const float*)d_in[8];
    const float* W1      = (const float*)d_in[9];
    const float* b1      = (const float*)d_in[10];
    const float* W2      = (const float*)d_in[11];
    const float* b2      = (const float*)d_in[12];
    const float* actor_W = (const float*)d_in[13];
    const float* actor_b = (const float*)d_in[14];
    float* out = (float*)d_out;

    float* ws = (float*)d_ws;
    float* Wxb    = ws;  ws += 128 * 320;
    float* Ta     = ws;  ws += 128 * 320;
    float* Tb     = ws;  ws += 128 * 320;
    float* leaf_c = ws;  ws += 128 * 64;
    float* hroot  = ws;  ws += 128 * 64;
    float* cb0    = ws;  ws += 128 * 1024 * 64;   // c, level-10 sized
    float* cb1    = ws;  ws += 128 * 512 * 64;    // c, level-9 sized
    u16* u16ws = (u16*)ws;
    u16* Uswz = u16ws;  u16ws += 128 * 320;       // 40960 bf16
    u16* hb0  = u16ws;  u16ws += 128 * 1024 * 64; // h bf16, level-10 sized
    u16* hb1  = u16ws;  u16ws += 128 * 512 * 64;  // h bf16, level-9 sized
    float* cb[2] = { cb0, cb1 };
    u16*   hb[2] = { hb0, hb1 };

    precompute_kernel<<<128, 320, 0, stream>>>(Wx, b_tree, Ua, Ub,
                                               Wxb, Uswz, leaf_c, Ta, Tb);
    level10_kernel<<<131072 / 4, 256, 0, stream>>>(x_idx, Wxb, Ta, Tb, leaf_c,
                                                   hb[0], cb[0]);
    int cur = 0;
    for (int d = 9; d >= 0; --d) {
        level_kernel<<<1 << d, 256, 0, stream>>>(hb[cur], cb[cur], Uswz, Wxb,
                                                 x_idx, d, hb[cur ^ 1], cb[cur ^ 1],
                                                 d == 0 ? hroot : nullptr);
        cur ^= 1;
    }
    head_kernel<<<128, 64, 0, stream>>>(hroot, W1, b1, W2, b2, W_ih, b_lstm,
                                        actor_W, actor_b, vm, out);
}

// Round 3
// 183.498 us; speedup vs baseline: 2.9503x; 1.8231x over previous
//
#include <hip/hip_runtime.h>

// ---------------------------------------------------------------------------
// SympleAgent Tree-LSTM on MI355X — R3: subtree-fused sweep.
// 3 launches: precompute -> sweepA (levels 10..4) -> sweepB (levels 3..0 + head).
// Key structure: row i at level d depends only on rows 2i,2i+1 at level d+1,
// so a block sweeps its subtree with h(bf16)/c(fp32) in LDS, U in registers.
// ---------------------------------------------------------------------------

typedef unsigned short u16;
typedef unsigned int   u32;
typedef __attribute__((ext_vector_type(8))) short  short8;   // 8 bf16
typedef __attribute__((ext_vector_type(4))) float  floatx4;  // MFMA C/D frag

__device__ __forceinline__ float fsig(float x) {
    return __fdividef(1.0f, 1.0f + __expf(-x));
}
__device__ __forceinline__ float ftanh(float x) {
    return 1.0f - __fdividef(2.0f, __expf(2.0f * x) + 1.0f);
}
__device__ __forceinline__ u16 f2bf(float x) {   // round-to-nearest-even
    u32 u = __float_as_uint(x);
    return (u16)((u + 0x7FFFu + ((u >> 16) & 1u)) >> 16);
}
__device__ __forceinline__ float bf2f(short s) {
    return __uint_as_float(((u32)(u16)s) << 16);
}
__device__ __forceinline__ float c_from_slots(short lo, short hi) {
    return __uint_as_float((u32)(u16)lo | (((u32)(u16)hi) << 16));
}

// LDS strides (elements): h rows padded to 72 u16 (144 B), c rows to 65 f32.
#define HS 72
#define CS 65

// ---------------- precompute: packed tables + swizzled U -------------------
// grid 128 (one block per vocab id), block 320.
// Wp [id][hh][8] u16 : slots 0..4 = bf16 gates (i,fa,fb,o,u) of Wx[id]+b.
// Tap[id][hh][8] u16 : slots 0..4 = bf16 of (leaf_h[id] @ Ua); 5,6 = leaf_c fp32.
// Tbp            : same with Ub.
// Uswz: B-fragment order, element ((kc*20+nt)*64+lane)*8+j =
//       U[kc*32+(lane>>4)*8+j][nt*16+(lane&15)], U = vstack(Ua,Ub) (128x320).
__global__ void precompute_kernel(
    const float* __restrict__ Wx, const float* __restrict__ b_tree,
    const float* __restrict__ Ua, const float* __restrict__ Ub,
    u16* __restrict__ Wp, u16* __restrict__ Tap, u16* __restrict__ Tbp,
    u16* __restrict__ Uswz)
{
    int v = blockIdx.x;
    int t = threadIdx.x;
    __shared__ float sz[320], sta[320], stb[320], sh[64], sc[64];
    float z = Wx[v * 320 + t] + b_tree[t];
    sz[t] = z;
    {   // Uswz: one element per thread (128*320 total)
        int f = v * 320 + t;
        int j = f & 7, lane = (f >> 3) & 63, tk = f >> 9;
        int nt = tk % 20, kc = tk / 20;
        int k = kc * 32 + (lane >> 4) * 8 + j;
        int nn = nt * 16 + (lane & 15);
        float uval = (k < 64) ? Ua[k * 320 + nn] : Ub[(k - 64) * 320 + nn];
        Uswz[f] = f2bf(uval);
    }
    __syncthreads();
    if (t < 64) {
        float c = fsig(sz[t]) * ftanh(sz[256 + t]);
        float h = fsig(sz[192 + t]) * ftanh(c);
        sc[t] = c; sh[t] = h;
    }
    __syncthreads();
    float ta = 0.f, tb = 0.f;
    #pragma unroll
    for (int k = 0; k < 64; ++k) {
        ta += sh[k] * Ua[k * 320 + t];
        tb += sh[k] * Ub[k * 320 + t];
    }
    sta[t] = ta; stb[t] = tb;
    __syncthreads();
    if (t < 64) {
        int hh = t;
        u32 cbits = __float_as_uint(sc[hh]);
        short8 wp, tp, bp;
        #pragma unroll
        for (int g = 0; g < 5; ++g) {
            wp[g] = (short)f2bf(sz[g * 64 + hh]);
            tp[g] = (short)f2bf(sta[g * 64 + hh]);
            bp[g] = (short)f2bf(stb[g * 64 + hh]);
        }
        wp[5] = 0; wp[6] = 0; wp[7] = 0;
        tp[5] = (short)(cbits & 0xFFFF); tp[6] = (short)(cbits >> 16); tp[7] = 0;
        bp[5] = tp[5]; bp[6] = tp[6]; bp[7] = 0;
        *(short8*)(Wp  + ((size_t)v * 64 + hh) * 8) = wp;
        *(short8*)(Tap + ((size_t)v * 64 + hh) * 8) = tp;
        *(short8*)(Tbp + ((size_t)v * 64 + hh) * 8) = bp;
    }
}

// ---------------- shared per-level GEMM + epilogue -------------------------
// One MFMA m-tile covers 16 output rows (padded; invalid rows guarded).
// Wave wv owns hidden cols [wv*16, wv*16+16) for ALL 5 gates
// (n-tiles {wv, 4+wv, 8+wv, 12+wv, 16+wv}), so the epilogue is in-register.
template<int MT>
__device__ __forceinline__ void sweep_level(
    const u16* hsrc, const float* csrc,          // LDS, level d+1 (children)
    u16* hdst, float* cdst,                      // LDS, level d (or null)
    u16* hg, float* cg,                          // global out (or null)
    float* hroot,                                // fp32 root h LDS (or null)
    const short8 Bfrag[4][5],
    const u16* __restrict__ Wp, const int* __restrict__ xb,
    int nrows, int i0, int loff,
    int lane15, int quad, int wv)
{
    floatx4 acc[MT][5];
    #pragma unroll
    for (int mt = 0; mt < MT; ++mt)
        #pragma unroll
        for (int g = 0; g < 5; ++g) acc[mt][g] = (floatx4){0.f, 0.f, 0.f, 0.f};

    #pragma unroll
    for (int mt = 0; mt < MT; ++mt) {
        #pragma unroll
        for (int kc = 0; kc < 4; ++kc) {
            int child = 2 * (mt * 16 + lane15) + (kc >> 1);
            short8 a = *(const short8*)(hsrc + child * HS + (kc & 1) * 32 + quad * 8);
            #pragma unroll
            for (int g = 0; g < 5; ++g)
                acc[mt][g] = __builtin_amdgcn_mfma_f32_16x16x32_bf16(
                    a, Bfrag[kc][g], acc[mt][g], 0, 0, 0);
        }
    }

    int hh = wv * 16 + lane15;
    #pragma unroll
    for (int mt = 0; mt < MT; ++mt) {
        #pragma unroll
        for (int r = 0; r < 4; ++r) {
            int row = mt * 16 + quad * 4 + r;
            bool valid = row < nrows;
            int id = xb[loff + i0 + row];   // garbage rows stay in-bounds
            short8 wp = *(const short8*)(Wp + (((size_t)id << 6) + hh) * 8);
            float zi  = acc[mt][0][r] + bf2f(wp[0]);
            float zfa = acc[mt][1][r] + bf2f(wp[1]);
            float zfb = acc[mt][2][r] + bf2f(wp[2]);
            float zo  = acc[mt][3][r] + bf2f(wp[3]);
            float zu  = acc[mt][4][r] + bf2f(wp[4]);
            float ca = csrc[(2 * row) * CS + hh];
            float cb = csrc[(2 * row + 1) * CS + hh];
            float c = fsig(zi) * ftanh(zu) + fsig(zfa) * ca + fsig(zfb) * cb;
            float h = fsig(zo) * ftanh(c);
            if (valid) {
                if (hdst)  { hdst[row * HS + hh] = f2bf(h); cdst[row * CS + hh] = c; }
                if (hg)    { hg[row * 64 + hh] = f2bf(h);   cg[row * 64 + hh] = c; }
                if (hroot) { hroot[hh] = h; }
            }
        }
    }
}

__device__ __forceinline__ void load_bfrags(short8 Bfrag[4][5],
                                            const u16* __restrict__ Uswz,
                                            int wv, int lane)
{
    #pragma unroll
    for (int kc = 0; kc < 4; ++kc)
        #pragma unroll
        for (int g = 0; g < 5; ++g) {
            int nt = g * 4 + wv;
            Bfrag[kc][g] = *(const short8*)(Uswz + ((kc * 20 + nt) * 64 + lane) * 8);
        }
}

// ---------------- phase A: levels 10..4, one block per 64-row subtree ------
// grid 2048 = 128 batches x 16 subtrees; block 256 (4 waves).
__global__ __launch_bounds__(256, 2) void sweepA_kernel(
    const int* __restrict__ x_idx,
    const u16* __restrict__ Wp, const u16* __restrict__ Tap,
    const u16* __restrict__ Tbp, const u16* __restrict__ Uswz,
    u16* __restrict__ h4, float* __restrict__ c4)
{
    __shared__ u16   hA[64 * HS];
    __shared__ u16   hB[32 * HS];
    __shared__ float cA[64 * CS];
    __shared__ float cB[32 * CS];
    int t = threadIdx.x, lane = t & 63, wv = t >> 6;
    int lane15 = lane & 15, quad = lane >> 4;
    int b = blockIdx.x >> 4, st = blockIdx.x & 15;
    const int* xb = x_idx + b * 4095;

    short8 Bfrag[4][5];
    load_bfrags(Bfrag, Uswz, wv, lane);

    // ---- level 10: pure table gather, 16 rows per wave, lane = hidden col
    #pragma unroll 2
    for (int rr = 0; rr < 16; ++rr) {
        int rl = wv * 16 + rr;
        int i = st * 64 + rl;
        int id  = xb[1023 + i];
        int ida = xb[2047 + 2 * i];
        int idb = xb[2048 + 2 * i];
        short8 wp = *(const short8*)(Wp  + (((size_t)id)  << 9) + lane * 8);
        short8 ta = *(const short8*)(Tap + (((size_t)ida) << 9) + lane * 8);
        short8 tb = *(const short8*)(Tbp + (((size_t)idb) << 9) + lane * 8);
        float zi  = bf2f(wp[0]) + bf2f(ta[0]) + bf2f(tb[0]);
        float zfa = bf2f(wp[1]) + bf2f(ta[1]) + bf2f(tb[1]);
        float zfb = bf2f(wp[2]) + bf2f(ta[2]) + bf2f(tb[2]);
        float zo  = bf2f(wp[3]) + bf2f(ta[3]) + bf2f(tb[3]);
        float zu  = bf2f(wp[4]) + bf2f(ta[4]) + bf2f(tb[4]);
        float ca = c_from_slots(ta[5], ta[6]);
        float cb = c_from_slots(tb[5], tb[6]);
        float c = fsig(zi) * ftanh(zu) + fsig(zfa) * ca + fsig(zfb) * cb;
        float h = fsig(zo) * ftanh(c);
        hA[rl * HS + lane] = f2bf(h);
        cA[rl * CS + lane] = c;
    }
    __syncthreads();
    // ---- level 9 (32 rows): A -> B
    sweep_level<2>(hA, cA, hB, cB, nullptr, nullptr, nullptr, Bfrag, Wp, xb,
                   32, st << 5, 511, lane15, quad, wv);
    __syncthreads();
    // ---- level 8 (16): B -> A
    sweep_level<1>(hB, cB, hA, cA, nullptr, nullptr, nullptr, Bfrag, Wp, xb,
                   16, st << 4, 255, lane15, quad, wv);
    __syncthreads();
    // ---- level 7 (8): A -> B
    sweep_level<1>(hA, cA, hB, cB, nullptr, nullptr, nullptr, Bfrag, Wp, xb,
                   8, st << 3, 127, lane15, quad, wv);
    __syncthreads();
    // ---- level 6 (4): B -> A
    sweep_level<1>(hB, cB, hA, cA, nullptr, nullptr, nullptr, Bfrag, Wp, xb,
                   4, st << 2, 63, lane15, quad, wv);
    __syncthreads();
    // ---- level 5 (2): A -> B
    sweep_level<1>(hA, cA, hB, cB, nullptr, nullptr, nullptr, Bfrag, Wp, xb,
                   2, st << 1, 31, lane15, quad, wv);
    __syncthreads();
    // ---- level 4 (1): B -> global
    sweep_level<1>(hB, cB, nullptr, nullptr,
                   h4 + (size_t)(b * 16 + st) * 64, c4 + (size_t)(b * 16 + st) * 64,
                   nullptr, Bfrag, Wp, xb, 1, st, 15, lane15, quad, wv);
}

// ---------------- phase B: levels 3..0 + head, one block per batch ---------
__global__ __launch_bounds__(256, 2) void sweepB_kernel(
    const int* __restrict__ x_idx,
    const u16* __restrict__ Wp, const u16* __restrict__ Uswz,
    const u16* __restrict__ h4, const float* __restrict__ c4,
    const float* __restrict__ W1, const float* __restrict__ b1,
    const float* __restrict__ W2, const float* __restrict__ b2,
    const float* __restrict__ W_ih, const float* __restrict__ b_lstm,
    const float* __restrict__ actor_W, const float* __restrict__ actor_b,
    const float* __restrict__ vm, float* __restrict__ out)
{
    __shared__ u16   hA[32 * HS];
    __shared__ u16   hB[32 * HS];
    __shared__ float cA[32 * CS];
    __shared__ float cB[32 * CS];
    __shared__ float hroot[64];
    int t = threadIdx.x, lane = t & 63, wv = t >> 6;
    int lane15 = lane & 15, quad = lane >> 4;
    int b = blockIdx.x;
    const int* xb = x_idx + b * 4095;

    short8 Bfrag[4][5];
    load_bfrags(Bfrag, Uswz, wv, lane);

    // stage level-4 state (16 rows)
    for (int idx = t; idx < 16 * 64; idx += 256) {
        int r = idx >> 6, hh = idx & 63;
        hA[r * HS + hh] = h4[(size_t)(b * 16 + r) * 64 + hh];
        cA[r * CS + hh] = c4[(size_t)(b * 16 + r) * 64 + hh];
    }
    __syncthreads();
    sweep_level<1>(hA, cA, hB, cB, nullptr, nullptr, nullptr, Bfrag, Wp, xb,
                   8, 0, 7, lane15, quad, wv);   // level 3
    __syncthreads();
    sweep_level<1>(hB, cB, hA, cA, nullptr, nullptr, nullptr, Bfrag, Wp, xb,
                   4, 0, 3, lane15, quad, wv);   // level 2
    __syncthreads();
    sweep_level<1>(hA, cA, hB, cB, nullptr, nullptr, nullptr, Bfrag, Wp, xb,
                   2, 0, 1, lane15, quad, wv);   // level 1
    __syncthreads();
    sweep_level<1>(hB, cB, nullptr, nullptr, nullptr, nullptr, hroot, Bfrag, Wp, xb,
                   1, 0, 0, lane15, quad, wv);   // level 0 -> fp32 root in LDS
    __syncthreads();

    // ---- head: wave 0 only, shuffle-based GEMVs
    if (wv == 0) {
        float a = b1[lane];
        #pragma unroll 8
        for (int k = 0; k < 64; ++k) a += hroot[k] * W1[k * 64 + lane];
        float r1 = fmaxf(a, 0.f);
        float f = b2[lane];
        #pragma unroll 8
        for (int k = 0; k < 64; ++k) f += __shfl(r1, k) * W2[k * 64 + lane];
        float gi = b_lstm[lane], gg = b_lstm[128 + lane], go = b_lstm[192 + lane];
        #pragma unroll 8
        for (int k = 0; k < 64; ++k) {
            float fk = __shfl(f, k);
            gi += fk * W_ih[k * 256 + lane];
            gg += fk * W_ih[k * 256 + 128 + lane];
            go += fk * W_ih[k * 256 + 192 + lane];
        }
        float cg = fsig(gi) * ftanh(gg);
        float hg = fsig(go) * ftanh(cg);
        int tt = (lane < 20) ? lane : 19;
        float dot = 0.f;
        #pragma unroll 8
        for (int k = 0; k < 64; ++k) {
            float fk = __shfl(f, k), hk = __shfl(hg, k);
            dot += fk * actor_W[k * 20 + tt] + hk * actor_W[(64 + k) * 20 + tt];
        }
        float m = vm[tt];
        float lg = logf(m) + dot * m + actor_b[tt] * m;
        float mx = -1e30f;
        #pragma unroll
        for (int j = 0; j < 20; ++j) mx = fmaxf(mx, __shfl(lg, j));
        float s = 0.f;
        #pragma unroll
        for (int j = 0; j < 20; ++j) s += __expf((__shfl(lg, j) - mx) * (1.0f / 3.0f));
        if (lane < 20) out[b * 20 + lane] = __expf((lg - mx) * (1.0f / 3.0f)) / s;
    }
}

// ---------------------------------------------------------------------------
extern "C" void kernel_launch(void* const* d_in, const int* in_sizes, int n_in,
                              void* d_out, int out_size, void* d_ws, size_t ws_size,
                              hipStream_t stream)
{
    const int*   x_idx   = (const int*)d_in[0];
    const float* vm      = (const float*)d_in[1];
    const float* Wx      = (const float*)d_in[2];
    const float* Ua      = (const float*)d_in[3];
    const float* Ub      = (const float*)d_in[4];
    const float* b_tree  = (const float*)d_in[5];
    const float* W_ih    = (const float*)d_in[6];
    const float* b_lstm  = (const float*)d_in[8];
    const float* W1      = (const float*)d_in[9];
    const float* b1      = (const float*)d_in[10];
    const float* W2      = (const float*)d_in[11];
    const float* b2      = (const float*)d_in[12];
    const float* actor_W = (const float*)d_in[13];
    const float* actor_b = (const float*)d_in[14];
    float* out = (float*)d_out;

    float* ws = (float*)d_ws;
    float* c4 = ws;  ws += 2048 * 64;          // level-4 c (128 batches x 16)
    u16* u = (u16*)ws;
    u16* Wp   = u;  u += 128 * 64 * 8;
    u16* Tap  = u;  u += 128 * 64 * 8;
    u16* Tbp  = u;  u += 128 * 64 * 8;
    u16* Uswz = u;  u += 128 * 320;
    u16* h4   = u;  u += 2048 * 64;            // level-4 h (bf16)

    precompute_kernel<<<128, 320, 0, stream>>>(Wx, b_tree, Ua, Ub,
                                               Wp, Tap, Tbp, Uswz);
    sweepA_kernel<<<2048, 256, 0, stream>>>(x_idx, Wp, Tap, Tbp, Uswz, h4, c4);
    sweepB_kernel<<<128, 256, 0, stream>>>(x_idx, Wp, Uswz, h4, c4,
                                           W1, b1, W2, b2, W_ih, b_lstm,
                                           actor_W, actor_b, vm, out);
}

// Round 5
// 182.039 us; speedup vs baseline: 2.9740x; 1.0080x over previous
//
#include <hip/hip_runtime.h>

// ---------------------------------------------------------------------------
// SympleAgent Tree-LSTM on MI355X — R5: zero-waste subtree sweep (fixed).
// precompute -> sweepA (L10..L7, grid 1024 = 128 batches x 8 subtrees of 128
// L10-rows, zero garbage rows) -> sweepB (L6..L0 + head, grid 128).
// Wave wv owns hidden cols [wv*16,wv*16+16) for all 5 gates (Bfrag in regs);
// every wave processes EVERY 16-row m-tile (R4's tl=wv split was wrong).
// h AND c in bf16 in LDS (c error is damped downstream; halves LDS -> 52 KB).
// ---------------------------------------------------------------------------

typedef unsigned short u16;
typedef unsigned int   u32;
typedef __attribute__((ext_vector_type(8))) short  short8;   // 8 bf16
typedef __attribute__((ext_vector_type(4))) float  floatx4;  // MFMA C/D frag

__device__ __forceinline__ float fsig(float x) {
    return __fdividef(1.0f, 1.0f + __expf(-x));
}
__device__ __forceinline__ float ftanh(float x) {
    return 1.0f - __fdividef(2.0f, __expf(2.0f * x) + 1.0f);
}
__device__ __forceinline__ u16 f2bfa(float x) {  // round-to-nearest
    return (u16)((__float_as_uint(x) + 0x8000u) >> 16);
}
__device__ __forceinline__ float bflo(u32 cc) { return __uint_as_float(cc << 16); }
__device__ __forceinline__ float bfhi(u32 cc) { return __uint_as_float(cc & 0xFFFF0000u); }

#define HS 72   // h LDS row stride (u16); 144 B keeps 16B-aligned b128 reads

// ---------------- precompute: fp32 packed tables + swizzled bf16 U ---------
// grid 128 (one block per vocab id), block 320.
// WpA [id][hh] float4 = gates (i,fa,fb,o) of Wx[id]+b;  WpU float = u gate.
// TaA/TaUC: same for leaf_h[id]@Ua, UC = (u_gate, leaf_c). TbA/TbUC: with Ub.
// Uswz: B-fragment order, element ((kc*20+nt)*64+lane)*8+j =
//       U[kc*32+(lane>>4)*8+j][nt*16+(lane&15)], U = vstack(Ua,Ub) (128x320).
__global__ void precompute_kernel(
    const float* __restrict__ Wx, const float* __restrict__ b_tree,
    const float* __restrict__ Ua, const float* __restrict__ Ub,
    float4* __restrict__ WpA, float* __restrict__ WpU,
    float4* __restrict__ TaA, float2* __restrict__ TaUC,
    float4* __restrict__ TbA, float2* __restrict__ TbUC,
    u16* __restrict__ Uswz)
{
    int v = blockIdx.x;
    int t = threadIdx.x;
    __shared__ float sz[320], sta[320], stb[320], sh[64], sc[64];
    float z = Wx[v * 320 + t] + b_tree[t];
    sz[t] = z;
    {   // Uswz: one element per thread (128*320 total)
        int f = v * 320 + t;
        int j = f & 7, lane = (f >> 3) & 63, tk = f >> 9;
        int nt = tk % 20, kc = tk / 20;
        int k = kc * 32 + (lane >> 4) * 8 + j;
        int nn = nt * 16 + (lane & 15);
        float uval = (k < 64) ? Ua[k * 320 + nn] : Ub[(k - 64) * 320 + nn];
        Uswz[f] = (u16)((__float_as_uint(uval) + 0x7FFFu +
                         ((__float_as_uint(uval) >> 16) & 1u)) >> 16);
    }
    __syncthreads();
    if (t < 64) {
        float c = fsig(sz[t]) * ftanh(sz[256 + t]);
        float h = fsig(sz[192 + t]) * ftanh(c);
        sc[t] = c; sh[t] = h;
    }
    __syncthreads();
    float ta = 0.f, tb = 0.f;
    #pragma unroll 8
    for (int k = 0; k < 64; ++k) {
        ta += sh[k] * Ua[k * 320 + t];
        tb += sh[k] * Ub[k * 320 + t];
    }
    sta[t] = ta; stb[t] = tb;
    __syncthreads();
    if (t < 64) {
        int o = (v << 6) + t;
        WpA[o]  = make_float4(sz[t],  sz[64 + t],  sz[128 + t],  sz[192 + t]);
        WpU[o]  = sz[256 + t];
        TaA[o]  = make_float4(sta[t], sta[64 + t], sta[128 + t], sta[192 + t]);
        TaUC[o] = make_float2(sta[256 + t], sc[t]);
        TbA[o]  = make_float4(stb[t], stb[64 + t], stb[128 + t], stb[192 + t]);
        TbUC[o] = make_float2(stb[256 + t], sc[t]);
    }
}

// ---------------- NT 16-row m-tiles: MFMA + fused gate epilogue ------------
// ALL waves process ALL tiles; wave wv covers hidden cols wv*16..wv*16+15.
// MODE 0: write LDS (hdst rows, cpd paired bf16).
// MODE 1: write global (hg row-major, cg paired bf16), node-indexed.
// MODE 2: write fp32 hroot (row 0 only).
template<int NT, int MODE>
__device__ __forceinline__ void sweep_level(
    const u16* hsrc, const u16* cps,             // LDS src (level d+1)
    u16* hdst, u16* cpd, u16* hg, u16* cg, float* hroot,
    const short8 Bfrag[4][5],
    const float4* __restrict__ WpA, const float* __restrict__ WpU,
    const int* __restrict__ xb, int loff, int lbase0, int node0,
    int lane15, int quad, int wv)
{
    floatx4 acc[NT][5];
    #pragma unroll
    for (int mt = 0; mt < NT; ++mt)
        #pragma unroll
        for (int g = 0; g < 5; ++g) acc[mt][g] = (floatx4){0.f, 0.f, 0.f, 0.f};

    #pragma unroll
    for (int mt = 0; mt < NT; ++mt) {
        #pragma unroll
        for (int kc = 0; kc < 4; ++kc) {
            int child = 2 * (lbase0 + mt * 16 + lane15) + (kc >> 1);
            short8 a = *(const short8*)(hsrc + child * HS + (kc & 1) * 32 + quad * 8);
            #pragma unroll
            for (int g = 0; g < 5; ++g)
                acc[mt][g] = __builtin_amdgcn_mfma_f32_16x16x32_bf16(
                    a, Bfrag[kc][g], acc[mt][g], 0, 0, 0);
        }
    }
    int hh = wv * 16 + lane15;
    #pragma unroll
    for (int mt = 0; mt < NT; ++mt) {
        #pragma unroll
        for (int r = 0; r < 4; ++r) {
            int lrow = lbase0 + mt * 16 + quad * 4 + r;
            int node = node0 + mt * 16 + quad * 4 + r;
            int id = xb[loff + node];
            float4 wg = WpA[(id << 6) + hh];
            float  wu = WpU[(id << 6) + hh];
            u32 cc = *(const u32*)(cps + lrow * 128 + hh * 2);
            float zi  = acc[mt][0][r] + wg.x;
            float zfa = acc[mt][1][r] + wg.y;
            float zfb = acc[mt][2][r] + wg.z;
            float zo  = acc[mt][3][r] + wg.w;
            float zu  = acc[mt][4][r] + wu;
            float c = fsig(zi) * ftanh(zu) + fsig(zfa) * bflo(cc) + fsig(zfb) * bfhi(cc);
            float h = fsig(zo) * ftanh(c);
            if (MODE == 0) {
                hdst[lrow * HS + hh] = f2bfa(h);
                cpd[(lrow >> 1) * 128 + hh * 2 + (lrow & 1)] = f2bfa(c);
            }
            if (MODE == 1) {
                hg[node * 64 + hh] = f2bfa(h);
                cg[(node >> 1) * 128 + hh * 2 + (node & 1)] = f2bfa(c);
            }
            if (MODE == 2) {
                if (lrow == 0) hroot[hh] = h;
            }
        }
    }
}

__device__ __forceinline__ void load_bfrags(short8 Bfrag[4][5],
                                            const u16* __restrict__ Uswz,
                                            int wv, int lane)
{
    #pragma unroll
    for (int kc = 0; kc < 4; ++kc)
        #pragma unroll
        for (int g = 0; g < 5; ++g) {
            int nt = g * 4 + wv;
            Bfrag[kc][g] = *(const short8*)(Uswz + ((kc * 20 + nt) * 64 + lane) * 8);
        }
}

// ---------------- phase A: L10 gather + L9,L8,L7 (zero waste) --------------
// grid 1024 = 128 batches x 8 subtrees (128 L10-rows each); block 256.
// LDS: 18432 + 16384 + 9216 + 8192 = 52224 B (< 64 KB; 2 blocks/CU).
__global__ __launch_bounds__(256, 2) void sweepA_kernel(
    const int* __restrict__ x_idx,
    const float4* __restrict__ WpA, const float* __restrict__ WpU,
    const float4* __restrict__ TaA, const float2* __restrict__ TaUC,
    const float4* __restrict__ TbA, const float2* __restrict__ TbUC,
    const u16* __restrict__ Uswz,
    u16* __restrict__ h7, u16* __restrict__ c7)
{
    __shared__ u16 hA[128 * HS];
    __shared__ u16 cA[64 * 128];     // paired bf16: [pair][hh][parity]
    __shared__ u16 hB[64 * HS];
    __shared__ u16 cB[32 * 128];
    int t = threadIdx.x, lane = t & 63, wv = t >> 6;
    int lane15 = lane & 15, quad = lane >> 4;
    int b = blockIdx.x >> 3, st = blockIdx.x & 7;
    const int* xb = x_idx + b * 4095;

    short8 Bfrag[4][5];
    load_bfrags(Bfrag, Uswz, wv, lane);

    // ---- level 10: table gather, 32 rows per wave, lane = hidden col
    #pragma unroll 2
    for (int rr = 0; rr < 32; ++rr) {
        int rl = wv * 32 + rr;
        int i = st * 128 + rl;
        int id  = xb[1023 + i];
        int ida = xb[2047 + 2 * i];
        int idb = xb[2048 + 2 * i];
        float4 wg  = WpA[(id  << 6) + lane];
        float  wu  = WpU[(id  << 6) + lane];
        float4 tga = TaA[(ida << 6) + lane];
        float2 tua = TaUC[(ida << 6) + lane];
        float4 tgb = TbA[(idb << 6) + lane];
        float2 tub = TbUC[(idb << 6) + lane];
        float zi  = wg.x + tga.x + tgb.x;
        float zfa = wg.y + tga.y + tgb.y;
        float zfb = wg.z + tga.z + tgb.z;
        float zo  = wg.w + tga.w + tgb.w;
        float zu  = wu   + tua.x + tub.x;
        float c = fsig(zi) * ftanh(zu) + fsig(zfa) * tua.y + fsig(zfb) * tub.y;
        float h = fsig(zo) * ftanh(c);
        hA[rl * HS + lane] = f2bfa(h);
        cA[(rl >> 1) * 128 + lane * 2 + (rl & 1)] = f2bfa(c);
    }
    __syncthreads();
    // ---- level 9: 64 rows = 4 tiles (2 calls of NT=2), hA/cA -> hB/cB
    sweep_level<2, 0>(hA, cA, hB, cB, nullptr, nullptr, nullptr, Bfrag, WpA, WpU,
                      xb, 511, 0,  st * 64,      lane15, quad, wv);
    sweep_level<2, 0>(hA, cA, hB, cB, nullptr, nullptr, nullptr, Bfrag, WpA, WpU,
                      xb, 511, 32, st * 64 + 32, lane15, quad, wv);
    __syncthreads();
    // ---- level 8: 32 rows = 2 tiles, hB/cB -> hA/cA
    sweep_level<2, 0>(hB, cB, hA, cA, nullptr, nullptr, nullptr, Bfrag, WpA, WpU,
                      xb, 255, 0, st * 32, lane15, quad, wv);
    __syncthreads();
    // ---- level 7: 16 rows = 1 tile, hA/cA -> global (node-indexed in batch)
    sweep_level<1, 1>(hA, cA, nullptr, nullptr,
                      h7 + (size_t)b * 8192, c7 + (size_t)b * 8192, nullptr,
                      Bfrag, WpA, WpU, xb, 127, 0, st * 16, lane15, quad, wv);
}

// ---------------- phase B: L6..L0 + head, one block per batch --------------
__global__ __launch_bounds__(256, 2) void sweepB_kernel(
    const int* __restrict__ x_idx,
    const float4* __restrict__ WpA, const float* __restrict__ WpU,
    const u16* __restrict__ Uswz,
    const u16* __restrict__ h7, const u16* __restrict__ c7,
    const float* __restrict__ W1, const float* __restrict__ b1,
    const float* __restrict__ W2, const float* __restrict__ b2,
    const float* __restrict__ W_ih, const float* __restrict__ b_lstm,
    const float* __restrict__ actor_W, const float* __restrict__ actor_b,
    const float* __restrict__ vm, float* __restrict__ out)
{
    __shared__ u16 hA[128 * HS];
    __shared__ u16 cA[64 * 128];
    __shared__ u16 hB[64 * HS];
    __shared__ u16 cB[32 * 128];
    __shared__ float hroot[64];
    int t = threadIdx.x, lane = t & 63, wv = t >> 6;
    int lane15 = lane & 15, quad = lane >> 4;
    int b = blockIdx.x;
    const int* xb = x_idx + b * 4095;
    const u16* h7b = h7 + (size_t)b * 8192;
    const u16* c7b = c7 + (size_t)b * 8192;

    short8 Bfrag[4][5];
    load_bfrags(Bfrag, Uswz, wv, lane);

    // stage L7 state: h 128 rows x 64, c paired (both bf16, u32 copies)
    for (int idx = t; idx < 4096; idx += 256) {
        int r = idx >> 5, p2 = (idx & 31) * 2;
        *(u32*)&hA[r * HS + p2] = *(const u32*)&h7b[r * 64 + p2];
        *(u32*)&cA[idx * 2] = *(const u32*)&c7b[idx * 2];
    }
    __syncthreads();
    // L6: 64 rows = 4 tiles
    sweep_level<2, 0>(hA, cA, hB, cB, nullptr, nullptr, nullptr, Bfrag, WpA, WpU,
                      xb, 63, 0, 0, lane15, quad, wv);
    sweep_level<2, 0>(hA, cA, hB, cB, nullptr, nullptr, nullptr, Bfrag, WpA, WpU,
                      xb, 63, 32, 32, lane15, quad, wv);
    __syncthreads();
    // L5: 32 rows
    sweep_level<2, 0>(hB, cB, hA, cA, nullptr, nullptr, nullptr, Bfrag, WpA, WpU,
                      xb, 31, 0, 0, lane15, quad, wv);
    __syncthreads();
    // L4: 16 rows
    sweep_level<1, 0>(hA, cA, hB, cB, nullptr, nullptr, nullptr, Bfrag, WpA, WpU,
                      xb, 15, 0, 0, lane15, quad, wv);
    __syncthreads();
    // L3: 8 valid (8 garbage rows computed from bounded stale data)
    sweep_level<1, 0>(hB, cB, hA, cA, nullptr, nullptr, nullptr, Bfrag, WpA, WpU,
                      xb, 7, 0, 0, lane15, quad, wv);
    __syncthreads();
    // L2: 4 valid
    sweep_level<1, 0>(hA, cA, hB, cB, nullptr, nullptr, nullptr, Bfrag, WpA, WpU,
                      xb, 3, 0, 0, lane15, quad, wv);
    __syncthreads();
    // L1: 2 valid
    sweep_level<1, 0>(hB, cB, hA, cA, nullptr, nullptr, nullptr, Bfrag, WpA, WpU,
                      xb, 1, 0, 0, lane15, quad, wv);
    __syncthreads();
    // L0 -> fp32 root
    sweep_level<1, 2>(hA, cA, nullptr, nullptr, nullptr, nullptr, hroot,
                      Bfrag, WpA, WpU, xb, 0, 0, 0, lane15, quad, wv);
    __syncthreads();

    // ---- head: wave 0 only, shuffle-based GEMVs
    if (wv == 0) {
        float a = b1[lane];
        #pragma unroll 8
        for (int k = 0; k < 64; ++k) a += hroot[k] * W1[k * 64 + lane];
        float r1 = fmaxf(a, 0.f);
        float f = b2[lane];
        #pragma unroll 8
        for (int k = 0; k < 64; ++k) f += __shfl(r1, k) * W2[k * 64 + lane];
        float gi = b_lstm[lane], gg = b_lstm[128 + lane], go = b_lstm[192 + lane];
        #pragma unroll 8
        for (int k = 0; k < 64; ++k) {
            float fk = __shfl(f, k);
            gi += fk * W_ih[k * 256 + lane];
            gg += fk * W_ih[k * 256 + 128 + lane];
            go += fk * W_ih[k * 256 + 192 + lane];
        }
        float cg = fsig(gi) * ftanh(gg);
        float hg = fsig(go) * ftanh(cg);
        int tt = (lane < 20) ? lane : 19;
        float dot = 0.f;
        #pragma unroll 8
        for (int k = 0; k < 64; ++k) {
            float fk = __shfl(f, k), hk = __shfl(hg, k);
            dot += fk * actor_W[k * 20 + tt] + hk * actor_W[(64 + k) * 20 + tt];
        }
        float m = vm[tt];
        float lg = logf(m) + dot * m + actor_b[tt] * m;
        float mx = -1e30f;
        #pragma unroll
        for (int j = 0; j < 20; ++j) mx = fmaxf(mx, __shfl(lg, j));
        float s = 0.f;
        #pragma unroll
        for (int j = 0; j < 20; ++j) s += __expf((__shfl(lg, j) - mx) * (1.0f / 3.0f));
        if (lane < 20) out[b * 20 + lane] = __expf((lg - mx) * (1.0f / 3.0f)) / s;
    }
}

// ---------------------------------------------------------------------------
extern "C" void kernel_launch(void* const* d_in, const int* in_sizes, int n_in,
                              void* d_out, int out_size, void* d_ws, size_t ws_size,
                              hipStream_t stream)
{
    const int*   x_idx   = (const int*)d_in[0];
    const float* vm      = (const float*)d_in[1];
    const float* Wx      = (const float*)d_in[2];
    const float* Ua      = (const float*)d_in[3];
    const float* Ub      = (const float*)d_in[4];
    const float* b_tree  = (const float*)d_in[5];
    const float* W_ih    = (const float*)d_in[6];
    const float* b_lstm  = (const float*)d_in[8];
    const float* W1      = (const float*)d_in[9];
    const float* b1      = (const float*)d_in[10];
    const float* W2      = (const float*)d_in[11];
    const float* b2      = (const float*)d_in[12];
    const float* actor_W = (const float*)d_in[13];
    const float* actor_b = (const float*)d_in[14];
    float* out = (float*)d_out;

    char* ws = (char*)d_ws;
    float4* WpA  = (float4*)ws;            ws += 128 * 64 * 16;
    float4* TaA  = (float4*)ws;            ws += 128 * 64 * 16;
    float4* TbA  = (float4*)ws;            ws += 128 * 64 * 16;
    float2* TaUC = (float2*)ws;            ws += 128 * 64 * 8;
    float2* TbUC = (float2*)ws;            ws += 128 * 64 * 8;
    float*  WpU  = (float*)ws;             ws += 128 * 64 * 4;
    u16*    h7   = (u16*)ws;               ws += 128 * 8192 * 2;
    u16*    c7   = (u16*)ws;               ws += 128 * 8192 * 2;
    u16*    Uswz = (u16*)ws;               ws += 128 * 320 * 2;

    precompute_kernel<<<128, 320, 0, stream>>>(Wx, b_tree, Ua, Ub,
                                               WpA, WpU, TaA, TaUC, TbA, TbUC, Uswz);
    sweepA_kernel<<<1024, 256, 0, stream>>>(x_idx, WpA, WpU, TaA, TaUC,
                                            TbA, TbUC, Uswz, h7, c7);
    sweepB_kernel<<<128, 256, 0, stream>>>(x_idx, WpA, WpU, Uswz, h7, c7,
                                           W1, b1, W2, b2, W_ih, b_lstm,
                                           actor_W, actor_b, vm, out);
}